// Round 1
// baseline (735.679 us; speedup 1.0000x reference)
//
#include <hip/hip_runtime.h>
#include <math.h>

// ---------------- problem constants ----------------
#define SR        32000
#define NFFT      1024
#define HOP       320
#define NMELS     128
#define NFREQS    513      // NFFT/2 + 1
#define LIN       128000   // samples per batch item
#define PADL      512      // NFFT/2 reflect pad
#define TFRAMES   401
#define NB        128      // batch

// ws layout in floats:
//   fb      : [NFREQS*NMELS] = 65664          @ 0
//   fstart  : [128] ints                      @ 65664
//   fend    : [128] ints                      @ 65792
//   mel     : [NB*TFRAMES*NMELS] = 6569984    @ 65920   (layout [B][T][M])
//   stats   : [NB*2]                          @ 6635904
#define WS_FB     0
#define WS_FSTART 65664
#define WS_FEND   65792
#define WS_MEL    65920
#define WS_STATS  (65920 + 6569984)

// ---------------- kernel 1: mel filterbank (fp64, torchaudio HTK defaults) ----------------
__global__ void fb_kernel(float* __restrict__ fb) {
    int f = blockIdx.x;      // 0..512
    int m = threadIdx.x;     // 0..127
    double freq = (double)f * ((double)SR * 0.5) / (double)(NFREQS - 1); // f * 31.25
    double mel_max = 2595.0 * log10(1.0 + ((double)SR * 0.5) / 700.0);
    double m0 = (double)(m)     * mel_max / (double)(NMELS + 1);
    double m1 = (double)(m + 1) * mel_max / (double)(NMELS + 1);
    double m2 = (double)(m + 2) * mel_max / (double)(NMELS + 1);
    double f0 = 700.0 * (pow(10.0, m0 / 2595.0) - 1.0);
    double f1 = 700.0 * (pow(10.0, m1 / 2595.0) - 1.0);
    double f2 = 700.0 * (pow(10.0, m2 / 2595.0) - 1.0);
    double down = (freq - f0) / (f1 - f0);
    double up   = (f2 - freq) / (f2 - f1);
    double v = fmin(down, up);
    v = fmax(0.0, v);
    fb[f * NMELS + m] = (float)v;
}

// ---------------- kernel 2: per-mel nonzero bounds ----------------
__global__ void fb_bounds_kernel(const float* __restrict__ fb,
                                 int* __restrict__ fstart, int* __restrict__ fend) {
    int m = threadIdx.x;     // 0..127
    int s = NFREQS, e = 0;
    for (int f = 0; f < NFREQS; ++f) {
        if (fb[f * NMELS + m] > 0.0f) {
            if (f < s) s = f;
            e = f + 1;
        }
    }
    if (s == NFREQS) { s = 0; e = 0; }
    fstart[m] = s;
    fend[m]   = e;
}

// ---------------- kernel 3: frame -> window -> FFT(1024) -> |X| -> sparse mel ----------------
// one block (256 threads) per (b, t) frame; mel written as [B][T][M] (coalesced)
__launch_bounds__(256)
__global__ void fft_mel_kernel(const float* __restrict__ x,
                               const float* __restrict__ fb,
                               const int* __restrict__ fstart,
                               const int* __restrict__ fend,
                               float* __restrict__ mel) {
    __shared__ float re[NFFT];
    __shared__ float im[NFFT];
    __shared__ float twr[NFFT / 2];
    __shared__ float twi[NFFT / 2];
    __shared__ float melp[2][NMELS];

    const int tid = threadIdx.x;
    const int bt  = blockIdx.x;             // b*TFRAMES + t
    const int b   = bt / TFRAMES;
    const int t   = bt - b * TFRAMES;
    const float* xb = x + (size_t)b * LIN;
    const int base = t * HOP - PADL;

    // load windowed frame (reflect pad) at bit-reversed LDS position
    for (int i = tid; i < NFFT; i += 256) {
        int q = base + i;
        q = (q < 0) ? -q : q;
        q = (q >= LIN) ? (2 * LIN - 2 - q) : q;
        float ang = (float)i * 6.135923151542565e-3f;     // 2*pi/1024
        float w = 0.5f - 0.5f * cosf(ang);
        int rev = (int)(__brev((unsigned)i) >> 22);       // 10-bit reverse
        re[rev] = xb[q] * w;
        im[rev] = 0.0f;
    }
    // twiddle table w_k = exp(-2*pi*i*k/1024), k=0..511
    for (int k = tid; k < NFFT / 2; k += 256) {
        float sg, cg;
        sincosf(-(float)M_PI / 512.0f * (float)k, &sg, &cg);
        twr[k] = cg;
        twi[k] = sg;
    }
    __syncthreads();

    // radix-2 DIT, 10 stages, 512 butterflies/stage, 2 per thread
    for (int s = 1; s <= 10; ++s) {
        const int half = 1 << (s - 1);
        const int m    = half << 1;
        for (int k = tid; k < NFFT / 2; k += 256) {
            const int j   = k & (half - 1);
            const int grp = k >> (s - 1);
            const int pos = grp * m + j;
            const int tix = j << (10 - s);
            const float wr = twr[tix], wi = twi[tix];
            const float vr = re[pos + half], vi = im[pos + half];
            const float tr = wr * vr - wi * vi;
            const float ti = wr * vi + wi * vr;
            const float ur = re[pos], ui = im[pos];
            re[pos]        = ur + tr;
            im[pos]        = ui + ti;
            re[pos + half] = ur - tr;
            im[pos + half] = ui - ti;
        }
        __syncthreads();
    }

    // magnitude of bins 0..512 (overwrite re[k])
    for (int k = tid; k < NFREQS; k += 256) {
        float a = re[k], c = im[k];
        re[k] = sqrtf(a * a + c * c);
    }
    __syncthreads();

    // sparse mel projection: thread (m, seg) handles every other nonzero bin
    {
        const int m   = tid & (NMELS - 1);
        const int seg = tid >> 7;
        const int fs = fstart[m], fe = fend[m];
        float acc = 0.0f;
        for (int f = fs + seg; f < fe; f += 2)
            acc = fmaf(re[f], fb[f * NMELS + m], acc);
        melp[seg][m] = acc;
    }
    __syncthreads();
    if (tid < NMELS)
        mel[(size_t)bt * NMELS + tid] = melp[0][tid] + melp[1][tid];
}

// ---------------- kernel 4: PCEN IIR + pcen + per-batch sum/sumsq ----------------
// one block per batch item, one thread per mel row
__launch_bounds__(128)
__global__ void pcen_kernel(const float* __restrict__ mel,
                            float* __restrict__ out,
                            float* __restrict__ stats) {
    const int b = blockIdx.x;
    const int m = threadIdx.x;
    const float* mr = mel + (size_t)b * TFRAMES * NMELS + m;   // stride NMELS in t
    float* orow = out + (size_t)b * NMELS * TFRAMES + (size_t)m * TFRAMES;

    float M = 0.0f;
    float sum = 0.0f, sumsq = 0.0f;
    for (int t = 0; t < TFRAMES; ++t) {
        float xt = mr[(size_t)t * NMELS];
        M = (t == 0) ? xt : fmaf(0.975f, M, 0.025f * xt);
        float smooth = expf(0.98f * logf(1e-6f + M));          // (eps+M)^0.98
        float p = sqrtf(xt / smooth + 2.0f) - 1.4142135623730951f;
        orow[t] = p;
        sum += p;
        sumsq = fmaf(p, p, sumsq);
    }

    __shared__ double ssum[NMELS];
    __shared__ double ssq[NMELS];
    ssum[m] = (double)sum;
    ssq[m]  = (double)sumsq;
    __syncthreads();
    for (int off = 64; off > 0; off >>= 1) {
        if (m < off) { ssum[m] += ssum[m + off]; ssq[m] += ssq[m + off]; }
        __syncthreads();
    }
    if (m == 0) {
        const double n = (double)(NMELS * TFRAMES);            // 51328
        double mean = ssum[0] / n;
        double var  = (ssq[0] - n * mean * mean) / (n - 1.0);
        double sd   = sqrt(var > 0.0 ? var : 0.0);
        stats[b * 2]     = (float)mean;
        stats[b * 2 + 1] = (float)(1.0 / (sd + 1e-6));
    }
}

// ---------------- kernel 5: in-place normalize (float4) ----------------
__global__ void norm_kernel(float* __restrict__ out, const float* __restrict__ stats) {
    const size_t n4 = (size_t)NB * NMELS * TFRAMES / 4;        // 1,642,496
    size_t i = (size_t)blockIdx.x * blockDim.x + threadIdx.x;
    if (i >= n4) return;
    int b = (int)((i * 4) / (NMELS * TFRAMES));                // 51328 % 4 == 0
    float mean = stats[b * 2];
    float inv  = stats[b * 2 + 1];
    float4 v = ((float4*)out)[i];
    v.x = (v.x - mean) * inv;
    v.y = (v.y - mean) * inv;
    v.z = (v.z - mean) * inv;
    v.w = (v.w - mean) * inv;
    ((float4*)out)[i] = v;
}

// ---------------- launch ----------------
extern "C" void kernel_launch(void* const* d_in, const int* in_sizes, int n_in,
                              void* d_out, int out_size, void* d_ws, size_t ws_size,
                              hipStream_t stream) {
    const float* x = (const float*)d_in[0];
    float* out = (float*)d_out;
    float* ws  = (float*)d_ws;

    float* fb     = ws + WS_FB;
    int*   fstart = (int*)(ws + WS_FSTART);
    int*   fend   = (int*)(ws + WS_FEND);
    float* mel    = ws + WS_MEL;
    float* stats  = ws + WS_STATS;

    fb_kernel<<<dim3(NFREQS), dim3(NMELS), 0, stream>>>(fb);
    fb_bounds_kernel<<<dim3(1), dim3(NMELS), 0, stream>>>(fb, fstart, fend);
    fft_mel_kernel<<<dim3(NB * TFRAMES), dim3(256), 0, stream>>>(x, fb, fstart, fend, mel);
    pcen_kernel<<<dim3(NB), dim3(NMELS), 0, stream>>>(mel, out, stats);

    const int n4 = NB * NMELS * TFRAMES / 4;
    norm_kernel<<<dim3((n4 + 255) / 256), dim3(256), 0, stream>>>(out, stats);
}

// Round 2
// 440.739 us; speedup vs baseline: 1.6692x; 1.6692x over previous
//
#include <hip/hip_runtime.h>
#include <math.h>

// ---------------- problem constants ----------------
#define SR        32000
#define NFFT      1024
#define HOP       320
#define NMELS     128
#define NFREQS    513      // NFFT/2 + 1
#define LIN       128000   // samples per batch item
#define PADL      512      // NFFT/2 reflect pad
#define TFRAMES   401
#define NB        128      // batch

// ws layout in floats:
//   fb      : [NFREQS*NMELS] = 65664          @ 0
//   fstart  : [128] ints                      @ 65664
//   fend    : [128] ints                      @ 65792
//   win     : [1024]                          @ 65920
//   tw      : [4 stages][3][256] float2 = 6144 floats @ 66944
//   mel     : [NB*TFRAMES*NMELS] = 6569984    @ 73088   (layout [B][T][M])
//   stats   : [NB*2]                          @ 73088 + 6569984
#define WS_FB     0
#define WS_FSTART 65664
#define WS_FEND   65792
#define WS_WIN    65920
#define WS_TW     66944
#define WS_MEL    73088
#define WS_STATS  (73088 + 6569984)

// ---------------- kernel 1: mel filterbank (fp64, torchaudio HTK defaults) ----------------
__global__ void fb_kernel(float* __restrict__ fb) {
    int f = blockIdx.x;      // 0..512
    int m = threadIdx.x;     // 0..127
    double freq = (double)f * ((double)SR * 0.5) / (double)(NFREQS - 1);
    double mel_max = 2595.0 * log10(1.0 + ((double)SR * 0.5) / 700.0);
    double m0 = (double)(m)     * mel_max / (double)(NMELS + 1);
    double m1 = (double)(m + 1) * mel_max / (double)(NMELS + 1);
    double m2 = (double)(m + 2) * mel_max / (double)(NMELS + 1);
    double f0 = 700.0 * (pow(10.0, m0 / 2595.0) - 1.0);
    double f1 = 700.0 * (pow(10.0, m1 / 2595.0) - 1.0);
    double f2 = 700.0 * (pow(10.0, m2 / 2595.0) - 1.0);
    double down = (freq - f0) / (f1 - f0);
    double up   = (f2 - freq) / (f2 - f1);
    double v = fmin(down, up);
    v = fmax(0.0, v);
    fb[f * NMELS + m] = (float)v;
}

// ---------------- kernel 2: per-mel nonzero bounds ----------------
__global__ void fb_bounds_kernel(const float* __restrict__ fb,
                                 int* __restrict__ fstart, int* __restrict__ fend) {
    int m = threadIdx.x;     // 0..127
    int s = NFREQS, e = 0;
    for (int f = 0; f < NFREQS; ++f) {
        if (fb[f * NMELS + m] > 0.0f) {
            if (f < s) s = f;
            e = f + 1;
        }
    }
    if (s == NFREQS) { s = 0; e = 0; }
    fstart[m] = s;
    fend[m]   = e;
}

// ---------------- kernel 2b: window + Stockham twiddle tables ----------------
__global__ void setup_kernel(float* __restrict__ win, float2* __restrict__ tw) {
    const int j = threadIdx.x;                  // 256 threads
    for (int i = j; i < NFFT; i += 256) {
        float ang = (float)i * (float)(2.0 * M_PI / (double)NFFT);
        win[i] = 0.5f - 0.5f * cosf(ang);
    }
    int Ns = 4;
    for (int si = 0; si < 4; ++si) {            // stages with Ns = 4,16,64,256
        int r = j & (Ns - 1);
        float base = -(float)M_PI * 0.5f * (float)r / (float)Ns;
        for (int t = 1; t <= 3; ++t) {
            float s, c;
            sincosf(base * (float)t, &s, &c);
            tw[(si * 3 + (t - 1)) * 256 + j] = make_float2(c, s);
        }
        Ns <<= 2;
    }
}

// ---------------- Stockham radix-4 helpers ----------------
// Bank swizzles: buffer A XORs row bits into bits[3:2]; buffer B into bits[1:0].
// Verified per 32-lane half: every stage's LDS access maps bijectively onto the
// 32 banks (worst case 2-way across wave64 = free).
__device__ __forceinline__ int swz(int i, int sel) {
    return sel ? (i ^ ((i >> 5) & 3)) : (i ^ (((i >> 5) & 3) << 2));
}

template<int NS, int SSEL, int DSEL, bool TW>
__device__ __forceinline__ void r4stage(const float* __restrict__ sre,
                                        const float* __restrict__ sim,
                                        float* __restrict__ dre,
                                        float* __restrict__ dim,
                                        const float2* __restrict__ twp,
                                        int j) {
    const int r = j & (NS - 1);
    float v0r = sre[swz(j,       SSEL)], v0i = sim[swz(j,       SSEL)];
    float v1r = sre[swz(j + 256, SSEL)], v1i = sim[swz(j + 256, SSEL)];
    float v2r = sre[swz(j + 512, SSEL)], v2i = sim[swz(j + 512, SSEL)];
    float v3r = sre[swz(j + 768, SSEL)], v3i = sim[swz(j + 768, SSEL)];
    if (TW) {
        float2 w1 = twp[j];
        float2 w2 = twp[256 + j];
        float2 w3 = twp[512 + j];
        float tr;
        tr = v1r * w1.x - v1i * w1.y; v1i = v1r * w1.y + v1i * w1.x; v1r = tr;
        tr = v2r * w2.x - v2i * w2.y; v2i = v2r * w2.y + v2i * w2.x; v2r = tr;
        tr = v3r * w3.x - v3i * w3.y; v3i = v3r * w3.y + v3i * w3.x; v3r = tr;
    }
    const float a0r = v0r + v2r, a0i = v0i + v2i;
    const float a1r = v0r - v2r, a1i = v0i - v2i;
    const float a2r = v1r + v3r, a2i = v1i + v3i;
    const float a3r = v1r - v3r, a3i = v1i - v3i;
    const int d = ((j & ~(NS - 1)) << 2) + r;
    dre[swz(d,          DSEL)] = a0r + a2r; dim[swz(d,          DSEL)] = a0i + a2i;
    dre[swz(d + NS,     DSEL)] = a1r + a3i; dim[swz(d + NS,     DSEL)] = a1i - a3r;
    dre[swz(d + 2 * NS, DSEL)] = a0r - a2r; dim[swz(d + 2 * NS, DSEL)] = a0i - a2i;
    dre[swz(d + 3 * NS, DSEL)] = a1r - a3i; dim[swz(d + 3 * NS, DSEL)] = a1i + a3r;
}

// ---------------- kernel 3: frame -> window -> Stockham radix-4 FFT -> |X| -> mel ----------------
__launch_bounds__(256)
__global__ void fft_mel_kernel(const float* __restrict__ x,
                               const float* __restrict__ win,
                               const float2* __restrict__ tw,
                               const float* __restrict__ fb,
                               const int* __restrict__ fstart,
                               const int* __restrict__ fend,
                               float* __restrict__ mel) {
    __shared__ float reA[NFFT], imA[NFFT], reB[NFFT], imB[NFFT];
    __shared__ float melp[2][NMELS];

    const int tid = threadIdx.x;
    const int bt  = blockIdx.x;
    const int b   = bt / TFRAMES;
    const int t   = bt - b * TFRAMES;
    const float* xb = x + (size_t)b * LIN;
    const int base = t * HOP - PADL;

    // windowed reflect-pad load into A (natural order)
    for (int i = tid; i < NFFT; i += 256) {
        int q = base + i;
        q = (q < 0) ? -q : q;
        q = (q >= LIN) ? (2 * LIN - 2 - q) : q;
        reA[swz(i, 0)] = xb[q] * win[i];
        imA[swz(i, 0)] = 0.0f;
    }
    __syncthreads();

    // 5 Stockham radix-4 stages (ping-pong A<->B), output in natural order in B
    r4stage<1,   0, 1, false>(reA, imA, reB, imB, nullptr,   tid); __syncthreads();
    r4stage<4,   1, 0, true >(reB, imB, reA, imA, tw,        tid); __syncthreads();
    r4stage<16,  0, 1, true >(reA, imA, reB, imB, tw + 768,  tid); __syncthreads();
    r4stage<64,  1, 0, true >(reB, imB, reA, imA, tw + 1536, tid); __syncthreads();
    r4stage<256, 0, 1, true >(reA, imA, reB, imB, tw + 2304, tid); __syncthreads();

    // magnitude of bins 0..512 -> reA (linear layout)
    for (int k = tid; k < NFREQS; k += 256) {
        const int p = swz(k, 1);
        float a = reB[p], c = imB[p];
        reA[k] = sqrtf(a * a + c * c);
    }
    __syncthreads();

    // sparse mel projection
    {
        const int m   = tid & (NMELS - 1);
        const int seg = tid >> 7;
        const int fs = fstart[m], fe = fend[m];
        float acc = 0.0f;
        for (int f = fs + seg; f < fe; f += 2)
            acc = fmaf(reA[f], fb[f * NMELS + m], acc);
        melp[seg][m] = acc;
    }
    __syncthreads();
    if (tid < NMELS)
        mel[(size_t)bt * NMELS + tid] = melp[0][tid] + melp[1][tid];
}

// ---------------- kernel 4: PCEN via exact chunked scan + per-batch stats ----------------
// one block (1024 thr) per batch item: 128 mel rows x 8 time-chunks
#define CHUNKS 8
#define CH0LEN 51            // 401 = 51 + 7*50
#define CHLEN  50
#define AFACT  0.28198814f   // 0.975^50

__launch_bounds__(1024)
__global__ void pcen_kernel(const float* __restrict__ mel,
                            float* __restrict__ out,
                            float* __restrict__ stats) {
    const int b   = blockIdx.x;
    const int tid = threadIdx.x;
    const int m   = tid & (NMELS - 1);
    const int c   = tid >> 7;                       // 0..7
    const int t0  = (c == 0) ? 0 : (CH0LEN + CHLEN * (c - 1));
    const int len = (c == 0) ? CH0LEN : CHLEN;
    const float* mb = mel + (size_t)b * TFRAMES * NMELS;

    __shared__ float Bc[CHUNKS][NMELS];

    // pass 1: per-chunk IIR partial with zero carry-in (chunk 0 uses true init)
    float M = 0.0f;
    if (c == 0) {
        M = mb[m];
        for (int t = 1; t < CH0LEN; ++t)
            M = fmaf(0.975f, M, 0.025f * mb[(size_t)t * NMELS + m]);
    } else {
        for (int t = t0; t < t0 + CHLEN; ++t)
            M = fmaf(0.975f, M, 0.025f * mb[(size_t)t * NMELS + m]);
    }
    Bc[c][m] = M;
    __syncthreads();

    // fold carries: M_in(c) = B_{c-1} + A*B_{c-2} + ... (A = 0.975^50)
    float Min = 0.0f;
    if (c > 0) {
        Min = Bc[0][m];
        for (int k = 1; k < c; ++k)
            Min = fmaf(AFACT, Min, Bc[k][m]);
    }

    // pass 2: exact sequential replay from correct carry + pcen + stats accumulate
    float* orow = out + (size_t)b * NMELS * TFRAMES + (size_t)m * TFRAMES;
    float sum = 0.0f, sumsq = 0.0f;
    M = Min;
    for (int t = t0; t < t0 + len; ++t) {
        float xt = mb[(size_t)t * NMELS + m];
        M = (t == 0) ? xt : fmaf(0.975f, M, 0.025f * xt);
        float smooth = __expf(0.98f * __logf(1e-6f + M));        // (eps+M)^0.98
        float p = sqrtf(xt / smooth + 2.0f) - 1.4142135623730951f;
        orow[t] = p;
        sum += p;
        sumsq = fmaf(p, p, sumsq);
    }

    // block reduction (wave shuffle + LDS of 16 wave partials), fp64 for stats
    double s = (double)sum, q = (double)sumsq;
    for (int off = 32; off > 0; off >>= 1) {
        s += __shfl_down(s, off);
        q += __shfl_down(q, off);
    }
    __shared__ double wsum[16], wsq[16];
    const int wid = tid >> 6, lane = tid & 63;
    if (lane == 0) { wsum[wid] = s; wsq[wid] = q; }
    __syncthreads();
    if (tid == 0) {
        double S = 0.0, Q = 0.0;
        for (int w = 0; w < 16; ++w) { S += wsum[w]; Q += wsq[w]; }
        const double n = (double)(NMELS * TFRAMES);
        double mean = S / n;
        double var  = (Q - n * mean * mean) / (n - 1.0);
        double sd   = sqrt(var > 0.0 ? var : 0.0);
        stats[b * 2]     = (float)mean;
        stats[b * 2 + 1] = (float)(1.0 / (sd + 1e-6));
    }
}

// ---------------- kernel 5: in-place normalize (float4) ----------------
__global__ void norm_kernel(float* __restrict__ out, const float* __restrict__ stats) {
    const size_t n4 = (size_t)NB * NMELS * TFRAMES / 4;
    size_t i = (size_t)blockIdx.x * blockDim.x + threadIdx.x;
    if (i >= n4) return;
    int b = (int)((i * 4) / (NMELS * TFRAMES));
    float mean = stats[b * 2];
    float inv  = stats[b * 2 + 1];
    float4 v = ((float4*)out)[i];
    v.x = (v.x - mean) * inv;
    v.y = (v.y - mean) * inv;
    v.z = (v.z - mean) * inv;
    v.w = (v.w - mean) * inv;
    ((float4*)out)[i] = v;
}

// ---------------- launch ----------------
extern "C" void kernel_launch(void* const* d_in, const int* in_sizes, int n_in,
                              void* d_out, int out_size, void* d_ws, size_t ws_size,
                              hipStream_t stream) {
    const float* x = (const float*)d_in[0];
    float* out = (float*)d_out;
    float* ws  = (float*)d_ws;

    float*  fb     = ws + WS_FB;
    int*    fstart = (int*)(ws + WS_FSTART);
    int*    fend   = (int*)(ws + WS_FEND);
    float*  win    = ws + WS_WIN;
    float2* tw     = (float2*)(ws + WS_TW);
    float*  mel    = ws + WS_MEL;
    float*  stats  = ws + WS_STATS;

    fb_kernel<<<dim3(NFREQS), dim3(NMELS), 0, stream>>>(fb);
    fb_bounds_kernel<<<dim3(1), dim3(NMELS), 0, stream>>>(fb, fstart, fend);
    setup_kernel<<<dim3(1), dim3(256), 0, stream>>>(win, tw);
    fft_mel_kernel<<<dim3(NB * TFRAMES), dim3(256), 0, stream>>>(x, win, tw, fb, fstart, fend, mel);
    pcen_kernel<<<dim3(NB), dim3(1024), 0, stream>>>(mel, out, stats);

    const int n4 = NB * NMELS * TFRAMES / 4;
    norm_kernel<<<dim3((n4 + 255) / 256), dim3(256), 0, stream>>>(out, stats);
}

// Round 3
// 319.042 us; speedup vs baseline: 2.3059x; 1.3814x over previous
//
#include <hip/hip_runtime.h>
#include <math.h>

// ---------------- problem constants ----------------
#define SR        32000
#define NFFT      1024
#define HOP       320
#define NMELS     128
#define NFREQS    513      // NFFT/2 + 1
#define LIN       128000   // samples per batch item
#define PADL      512      // NFFT/2 reflect pad
#define TFRAMES   401
#define NB        128      // batch

// ws layout in floats:
//   fb      : [NFREQS*NMELS] = 65664          @ 0
//   fstart  : [128] ints                      @ 65664
//   fend    : [128] ints                      @ 65792
//   win     : [1024]                          @ 65920
//   tw      : [4 stages][3][256] float2       @ 66944  (6144 floats)
//   mel     : [NB*TFRAMES*NMELS] = 6569984    @ 73088  (layout [B][T][M])
#define WS_FB     0
#define WS_FSTART 65664
#define WS_FEND   65792
#define WS_WIN    65920
#define WS_TW     66944
#define WS_MEL    73088

// ---------------- kernel 1: fused prep (window + twiddles + mel filterbank + bounds) ----------------
__global__ void prep_kernel(float* __restrict__ win, float2* __restrict__ tw,
                            float* __restrict__ fb,
                            int* __restrict__ fstart, int* __restrict__ fend) {
    const int tid = threadIdx.x;                // 256 threads, 1 block

    // periodic hann window
    for (int i = tid; i < NFFT; i += 256) {
        float ang = (float)i * (float)(2.0 * M_PI / (double)NFFT);
        win[i] = 0.5f - 0.5f * cosf(ang);
    }

    // Stockham twiddles, stages Ns = 4,16,64,256
    int Ns = 4;
    for (int si = 0; si < 4; ++si) {
        int r = tid & (Ns - 1);
        float base = -(float)M_PI * 0.5f * (float)r / (float)Ns;
        for (int t = 1; t <= 3; ++t) {
            float s, c;
            sincosf(base * (float)t, &s, &c);
            tw[(si * 3 + (t - 1)) * 256 + tid] = make_float2(c, s);
        }
        Ns <<= 2;
    }

    // mel filterbank: closed-form nonzero band per filter (fp64, HTK mel)
    if (tid < NMELS) {
        const int m = tid;
        const double mel_max = 2595.0 * log10(1.0 + ((double)SR * 0.5) / 700.0);
        const double m0 = (double)(m)     * mel_max / (double)(NMELS + 1);
        const double m1 = (double)(m + 1) * mel_max / (double)(NMELS + 1);
        const double m2 = (double)(m + 2) * mel_max / (double)(NMELS + 1);
        const double f0 = 700.0 * (pow(10.0, m0 / 2595.0) - 1.0);
        const double f1 = 700.0 * (pow(10.0, m1 / 2595.0) - 1.0);
        const double f2 = 700.0 * (pow(10.0, m2 / 2595.0) - 1.0);
        const double binw = (double)SR * 0.5 / (double)(NFREQS - 1);   // 31.25
        int fs = (int)(f0 / binw) + 1;
        int fe = (int)ceil(f2 / binw);
        fs = (fs > 0) ? fs - 1 : 0;            // widen by 1 for fp-rounding safety
        fe = (fe < NFREQS) ? fe + 1 : NFREQS;
        for (int f = fs; f < fe; ++f) {
            double freq = (double)f * binw;
            double down = (freq - f0) / (f1 - f0);
            double up   = (f2 - freq) / (f2 - f1);
            double v = fmin(down, up);
            v = fmax(0.0, v);
            fb[f * NMELS + m] = (float)v;
        }
        fstart[m] = fs;
        fend[m]   = fe;
    }
}

// ---------------- Stockham radix-4 helpers ----------------
// Bank swizzles: buffer A XORs row bits into bits[3:2]; buffer B into bits[1:0].
__device__ __forceinline__ int swz(int i, int sel) {
    return sel ? (i ^ ((i >> 5) & 3)) : (i ^ (((i >> 5) & 3) << 2));
}

template<int NS, int SSEL, int DSEL, bool TW>
__device__ __forceinline__ void r4stage(const float* __restrict__ sre,
                                        const float* __restrict__ sim,
                                        float* __restrict__ dre,
                                        float* __restrict__ dim,
                                        const float2* __restrict__ twp,
                                        int j) {
    const int r = j & (NS - 1);
    float v0r = sre[swz(j,       SSEL)], v0i = sim[swz(j,       SSEL)];
    float v1r = sre[swz(j + 256, SSEL)], v1i = sim[swz(j + 256, SSEL)];
    float v2r = sre[swz(j + 512, SSEL)], v2i = sim[swz(j + 512, SSEL)];
    float v3r = sre[swz(j + 768, SSEL)], v3i = sim[swz(j + 768, SSEL)];
    if (TW) {
        float2 w1 = twp[j];
        float2 w2 = twp[256 + j];
        float2 w3 = twp[512 + j];
        float tr;
        tr = v1r * w1.x - v1i * w1.y; v1i = v1r * w1.y + v1i * w1.x; v1r = tr;
        tr = v2r * w2.x - v2i * w2.y; v2i = v2r * w2.y + v2i * w2.x; v2r = tr;
        tr = v3r * w3.x - v3i * w3.y; v3i = v3r * w3.y + v3i * w3.x; v3r = tr;
    }
    const float a0r = v0r + v2r, a0i = v0i + v2i;
    const float a1r = v0r - v2r, a1i = v0i - v2i;
    const float a2r = v1r + v3r, a2i = v1i + v3i;
    const float a3r = v1r - v3r, a3i = v1i - v3i;
    const int d = ((j & ~(NS - 1)) << 2) + r;
    dre[swz(d,          DSEL)] = a0r + a2r; dim[swz(d,          DSEL)] = a0i + a2i;
    dre[swz(d + NS,     DSEL)] = a1r + a3i; dim[swz(d + NS,     DSEL)] = a1i - a3r;
    dre[swz(d + 2 * NS, DSEL)] = a0r - a2r; dim[swz(d + 2 * NS, DSEL)] = a0i - a2i;
    dre[swz(d + 3 * NS, DSEL)] = a1r - a3i; dim[swz(d + 3 * NS, DSEL)] = a1i + a3r;
}

// ---------------- kernel 2: TWO real frames per complex FFT -> |X| -> mel ----------------
// block q*401+t handles batches b0=2q, b1=2q+1 at frame t.  z = w*x0 + i*w*x1.
__launch_bounds__(256)
__global__ void fft_mel_kernel(const float* __restrict__ x,
                               const float* __restrict__ win,
                               const float2* __restrict__ tw,
                               const float* __restrict__ fb,
                               const int* __restrict__ fstart,
                               const int* __restrict__ fend,
                               float* __restrict__ mel) {
    __shared__ float reA[NFFT], imA[NFFT], reB[NFFT], imB[NFFT];

    const int tid = threadIdx.x;
    const int bid = blockIdx.x;
    const int q   = bid / TFRAMES;
    const int t   = bid - q * TFRAMES;
    const int b0  = 2 * q;
    const float* xb0 = x + (size_t)b0 * LIN;
    const float* xb1 = xb0 + LIN;
    const int base = t * HOP - PADL;

    // windowed reflect-pad load of both frames (packed complex)
    for (int i = tid; i < NFFT; i += 256) {
        int p = base + i;
        p = (p < 0) ? -p : p;
        p = (p >= LIN) ? (2 * LIN - 2 - p) : p;
        float w = win[i];
        reA[swz(i, 0)] = xb0[p] * w;
        imA[swz(i, 0)] = xb1[p] * w;
    }
    __syncthreads();

    // 5 Stockham radix-4 stages (ping-pong A<->B); natural order result in B
    r4stage<1,   0, 1, false>(reA, imA, reB, imB, nullptr,   tid); __syncthreads();
    r4stage<4,   1, 0, true >(reB, imB, reA, imA, tw,        tid); __syncthreads();
    r4stage<16,  0, 1, true >(reA, imA, reB, imB, tw + 768,  tid); __syncthreads();
    r4stage<64,  1, 0, true >(reB, imB, reA, imA, tw + 1536, tid); __syncthreads();
    r4stage<256, 0, 1, true >(reA, imA, reB, imB, tw + 2304, tid); __syncthreads();

    // Hermitian unpack + magnitudes: frame0 -> reA[k], frame1 -> imA[k] (linear)
    for (int k = tid; k < NFREQS; k += 256) {
        const int j = (NFFT - k) & (NFFT - 1);
        const int pk = swz(k, 1), pj = swz(j, 1);
        float a = reB[pk], b = imB[pk];
        float c = reB[pj], d = imB[pj];
        float x1r = a + c, x1i = b - d;          // 2*X0[k]
        float x2r = b + d, x2i = c - a;          // 2*X1[k]
        reA[k] = 0.5f * sqrtf(x1r * x1r + x1i * x1i);
        imA[k] = 0.5f * sqrtf(x2r * x2r + x2i * x2i);
    }
    __syncthreads();

    // sparse mel projection: tid<128 -> frame0/m, tid>=128 -> frame1/m
    {
        const int m  = tid & (NMELS - 1);
        const int fr = tid >> 7;
        const float* mag = fr ? imA : reA;
        const int fs = fstart[m], fe = fend[m];
        float acc = 0.0f;
        for (int f = fs; f < fe; ++f)
            acc = fmaf(mag[f], fb[f * NMELS + m], acc);
        mel[((size_t)(b0 + fr) * TFRAMES + t) * NMELS + m] = acc;
    }
}

// ---------------- kernel 3: PCEN chunked-scan + stats + fused normalize ----------------
// one block (1024 thr) per batch item: 128 mel rows x 8 time-chunks, chunk in registers
#define CHUNKS 8
#define CH0LEN 51            // 401 = 51 + 7*50
#define CHLEN  50
#define AFACT  0.28198814f   // 0.975^50

__launch_bounds__(1024)
__global__ void pcen_kernel(const float* __restrict__ mel,
                            float* __restrict__ out) {
    const int b   = blockIdx.x;
    const int tid = threadIdx.x;
    const int m   = tid & (NMELS - 1);
    const int c   = tid >> 7;                       // 0..7 (wave-uniform)
    const int t0  = (c == 0) ? 0 : (CH0LEN + CHLEN * (c - 1));
    const int len = (c == 0) ? CH0LEN : CHLEN;
    const float* mb = mel + (size_t)b * TFRAMES * NMELS;

    // load chunk into registers (static indexing)
    float v[CH0LEN];
#pragma unroll
    for (int i = 0; i < CH0LEN; ++i)
        if (i < len) v[i] = mb[(size_t)(t0 + i) * NMELS + m];

    // pass 1: per-chunk IIR partial with zero carry-in (chunk 0 = true init)
    float M;
    if (c == 0) {
        M = v[0];
#pragma unroll
        for (int i = 1; i < CH0LEN; ++i) M = fmaf(0.975f, M, 0.025f * v[i]);
    } else {
        M = 0.0f;
#pragma unroll
        for (int i = 0; i < CHLEN; ++i) M = fmaf(0.975f, M, 0.025f * v[i]);
    }
    __shared__ float Bc[CHUNKS][NMELS];
    Bc[c][m] = M;
    __syncthreads();

    // fold carries: M_in(c) = B_{c-1} + A*B_{c-2} + ...  (A = 0.975^50)
    float Min = 0.0f;
    if (c > 0) {
        Min = Bc[0][m];
        for (int k = 1; k < c; ++k) Min = fmaf(AFACT, Min, Bc[k][m]);
    }

    // pass 2: exact replay from carry; pcen into v[]; accumulate stats
    M = Min;
    float sum = 0.0f, sumsq = 0.0f;
#pragma unroll
    for (int i = 0; i < CH0LEN; ++i) {
        if (i < len) {
            float xt = v[i];
            M = (c == 0 && i == 0) ? xt : fmaf(0.975f, M, 0.025f * xt);
            float smooth = __expf(0.98f * __logf(1e-6f + M));     // (eps+M)^0.98
            float p = sqrtf(xt / smooth + 2.0f) - 1.4142135623730951f;
            v[i] = p;
            sum += p;
            sumsq = fmaf(p, p, sumsq);
        }
    }

    // block reduction in fp64
    double s = (double)sum, qq = (double)sumsq;
    for (int off = 32; off > 0; off >>= 1) {
        s  += __shfl_down(s, off);
        qq += __shfl_down(qq, off);
    }
    __shared__ double wsum[16], wsq[16];
    __shared__ float bmean, binv;
    const int wid = tid >> 6, lane = tid & 63;
    if (lane == 0) { wsum[wid] = s; wsq[wid] = qq; }
    __syncthreads();
    if (tid == 0) {
        double S = 0.0, Q = 0.0;
        for (int w = 0; w < 16; ++w) { S += wsum[w]; Q += wsq[w]; }
        const double n = (double)(NMELS * TFRAMES);
        double mean = S / n;
        double var  = (Q - n * mean * mean) / (n - 1.0);
        double sd   = sqrt(var > 0.0 ? var : 0.0);
        bmean = (float)mean;
        binv  = (float)(1.0 / (sd + 1e-6));
    }
    __syncthreads();
    const float mean = bmean, inv = binv;

    // fused normalize + store
    float* orow = out + (size_t)b * NMELS * TFRAMES + (size_t)m * TFRAMES + t0;
#pragma unroll
    for (int i = 0; i < CH0LEN; ++i)
        if (i < len) orow[i] = (v[i] - mean) * inv;
}

// ---------------- launch ----------------
extern "C" void kernel_launch(void* const* d_in, const int* in_sizes, int n_in,
                              void* d_out, int out_size, void* d_ws, size_t ws_size,
                              hipStream_t stream) {
    const float* x = (const float*)d_in[0];
    float* out = (float*)d_out;
    float* ws  = (float*)d_ws;

    float*  fb     = ws + WS_FB;
    int*    fstart = (int*)(ws + WS_FSTART);
    int*    fend   = (int*)(ws + WS_FEND);
    float*  win    = ws + WS_WIN;
    float2* tw     = (float2*)(ws + WS_TW);
    float*  mel    = ws + WS_MEL;

    prep_kernel<<<dim3(1), dim3(256), 0, stream>>>(win, tw, fb, fstart, fend);
    fft_mel_kernel<<<dim3((NB / 2) * TFRAMES), dim3(256), 0, stream>>>(
        x, win, tw, fb, fstart, fend, mel);
    pcen_kernel<<<dim3(NB), dim3(1024), 0, stream>>>(mel, out);
}

// Round 4
// 206.009 us; speedup vs baseline: 3.5711x; 1.5487x over previous
//
#include <hip/hip_runtime.h>
#include <math.h>

// ---------------- problem constants ----------------
#define SR        32000
#define NFFT      1024
#define HOP       320
#define NMELS     128
#define NFREQS    513      // NFFT/2 + 1
#define LIN       128000   // samples per batch item
#define PADL      512      // NFFT/2 reflect pad
#define TFRAMES   401
#define NB        128      // batch

// ws layout (float indices):
//   win      : [1024]                      @ 0
//   fbT      : [128][514]                  @ 1024      (65792)
//   fstart   : [128] ints                  @ 66816
//   fend     : [128] ints                  @ 66944
//   partials : [128*4*2] doubles           @ 67072     (2048 float slots, 8B aligned)
//   mel      : [NB*TFRAMES*NMELS]          @ 69120     (layout [B][T][M])
#define WS_WIN    0
#define WS_FBT    1024
#define WS_FS     66816
#define WS_FE     66944
#define WS_PART   67072
#define WS_MEL    69120
#define FBSTRIDE  514

// ---------------- kernel 1: prep (window + transposed mel filterbank + bounds) ----------------
__global__ void prep_kernel(float* __restrict__ win, float* __restrict__ fbT,
                            int* __restrict__ fstart, int* __restrict__ fend) {
    const int tid = threadIdx.x;                // 256 threads, 1 block

    for (int i = tid; i < NFFT; i += 256) {
        float ang = (float)i * (float)(2.0 * M_PI / (double)NFFT);
        win[i] = 0.5f - 0.5f * cosf(ang);       // periodic hann
    }

    if (tid < NMELS) {
        const int m = tid;
        const double mel_max = 2595.0 * log10(1.0 + ((double)SR * 0.5) / 700.0);
        const double m0 = (double)(m)     * mel_max / (double)(NMELS + 1);
        const double m1 = (double)(m + 1) * mel_max / (double)(NMELS + 1);
        const double m2 = (double)(m + 2) * mel_max / (double)(NMELS + 1);
        const double f0 = 700.0 * (pow(10.0, m0 / 2595.0) - 1.0);
        const double f1 = 700.0 * (pow(10.0, m1 / 2595.0) - 1.0);
        const double f2 = 700.0 * (pow(10.0, m2 / 2595.0) - 1.0);
        const double binw = (double)SR * 0.5 / (double)(NFREQS - 1);   // 31.25
        int fs = (int)(f0 / binw) + 1;
        int fe = (int)ceil(f2 / binw);
        fs = (fs > 0) ? fs - 1 : 0;            // widen by 1 for fp-rounding safety
        fe = (fe < NFREQS) ? fe + 1 : NFREQS;
        for (int f = fs; f < fe; ++f) {
            double freq = (double)f * binw;
            double down = (freq - f0) / (f1 - f0);
            double up   = (f2 - freq) / (f2 - f1);
            double v = fmin(down, up);
            v = fmax(0.0, v);
            fbT[m * FBSTRIDE + f] = (float)v;
        }
        fstart[m] = fs;
        fend[m]   = fe;
    }
}

// ---------------- register DFT-16 (radix-4 x radix-4, forward, W16 = e^{-2pi i/16}) ----------------
__device__ __forceinline__ void dft16(float (&xr)[16], float (&xi)[16]) {
    const float C8 = 0.92387953251128674f;
    const float S8 = 0.38268343236508978f;
    const float R2 = 0.70710678118654752f;
    // W16^{j0*ka} twiddles, [j0][ka]
    const float WR[4][4] = {{1,1,1,1},{1, C8, R2, S8},{1, R2, 0.f,-R2},{1, S8,-R2,-C8}};
    const float WI[4][4] = {{0,0,0,0},{0,-S8,-R2,-C8},{0,-R2,-1.f,-R2},{0,-C8,-R2, S8}};
    float pr[4][4], pi[4][4];
#pragma unroll
    for (int j0 = 0; j0 < 4; ++j0) {
        float ar = xr[j0],      ai = xi[j0];
        float br = xr[j0 + 4],  bi = xi[j0 + 4];
        float cr = xr[j0 + 8],  ci = xi[j0 + 8];
        float dr = xr[j0 + 12], di = xi[j0 + 12];
        float t0r = ar + cr, t0i = ai + ci;
        float t1r = ar - cr, t1i = ai - ci;
        float t2r = br + dr, t2i = bi + di;
        float t3r = br - dr, t3i = bi - di;
        pr[j0][0] = t0r + t2r; pi[j0][0] = t0i + t2i;
        pr[j0][1] = t1r + t3i; pi[j0][1] = t1i - t3r;    // t1 - i*t3
        pr[j0][2] = t0r - t2r; pi[j0][2] = t0i - t2i;
        pr[j0][3] = t1r - t3i; pi[j0][3] = t1i + t3r;    // t1 + i*t3
    }
#pragma unroll
    for (int ka = 0; ka < 4; ++ka) {
        float q0r = pr[0][ka], q0i = pi[0][ka];
        float q1r = pr[1][ka] * WR[1][ka] - pi[1][ka] * WI[1][ka];
        float q1i = pr[1][ka] * WI[1][ka] + pi[1][ka] * WR[1][ka];
        float q2r = pr[2][ka] * WR[2][ka] - pi[2][ka] * WI[2][ka];
        float q2i = pr[2][ka] * WI[2][ka] + pi[2][ka] * WR[2][ka];
        float q3r = pr[3][ka] * WR[3][ka] - pi[3][ka] * WI[3][ka];
        float q3i = pr[3][ka] * WI[3][ka] + pi[3][ka] * WR[3][ka];
        float t0r = q0r + q2r, t0i = q0i + q2i;
        float t1r = q0r - q2r, t1i = q0i - q2i;
        float t2r = q1r + q3r, t2i = q1i + q3i;
        float t3r = q1r - q3r, t3i = q1i - q3i;
        xr[ka]      = t0r + t2r; xi[ka]      = t0i + t2i;
        xr[ka + 4]  = t1r + t3i; xi[ka + 4]  = t1i - t3r;
        xr[ka + 8]  = t0r - t2r; xi[ka + 8]  = t0i - t2i;
        xr[ka + 12] = t1r - t3i; xi[ka + 12] = t1i + t3r;
    }
}

// ---------------- kernel 2: wave-resident FFT (16x16x4) -> |X| -> mel ----------------
// one WAVE per packed frame-pair (batches 2q, 2q+1 at frame tf); 4 waves/block; no __syncthreads.
__launch_bounds__(256)
__global__ void fft_mel_kernel(const float* __restrict__ x,
                               const float* __restrict__ win,
                               const float* __restrict__ fbT,
                               const int* __restrict__ fstart,
                               const int* __restrict__ fend,
                               float* __restrict__ mel) {
    __shared__ __align__(16) float2 buf[4][NFFT];   // per-wave transpose/E scratch
    __shared__ float2 magb[4][514];                 // per-wave |X| (frame0,frame1)

    const int w = threadIdx.x >> 6;       // wave in block
    const int t = threadIdx.x & 63;       // lane
    const int task = blockIdx.x * 4 + w;  // 0..25663
    const int q  = task / TFRAMES;
    const int tf = task - q * TFRAMES;
    const float* xb0 = x + (size_t)(2 * q) * LIN;
    const float* xb1 = xb0 + LIN;
    const int base = tf * HOP - PADL;

    // ---- load 16 samples/lane (stride 64), windowed, packed z = w*x0 + i*w*x1 ----
    float xr[16], xi[16];
#pragma unroll
    for (int j = 0; j < 16; ++j) {
        int n = t + 64 * j;
        int p = base + n;
        p = (p < 0) ? -p : p;
        p = (p >= LIN) ? (2 * LIN - 2 - p) : p;
        float wv = win[n];
        xr[j] = xb0[p] * wv;
        xi[j] = xb1[p] * wv;
    }

    // ---- stage 1: DFT-16 over j, twiddle W1024^{t*k1} ----
    dft16(xr, xi);
    {
        float sw, cw;
        sincosf((float)t * -6.135923151542565e-3f, &sw, &cw);   // -2pi t/1024
        float ur = 1.0f, ui = 0.0f;
#pragma unroll
        for (int k1 = 1; k1 < 16; ++k1) {
            float nr = ur * cw - ui * sw;
            ui = ur * sw + ui * cw;
            ur = nr;
            float tr = xr[k1] * ur - xi[k1] * ui;
            xi[k1] = xr[k1] * ui + xi[k1] * ur;
            xr[k1] = tr;
        }
    }

    // ---- transpose 1: write B at phi(k1*64+t), phi = u ^ ((u>>6 & 3)<<2) ----
    float2* B = buf[w];
#pragma unroll
    for (int k1 = 0; k1 < 16; ++k1)
        B[k1 * 64 + (t ^ ((k1 & 3) << 2))] = make_float2(xr[k1], xi[k1]);

    const int g = t >> 2, s = t & 3;
    const int c2 = g & 3;
#pragma unroll
    for (int j = 0; j < 16; ++j) {
        float2 v = B[g * 64 + s + 4 * (j ^ c2)];
        xr[j] = v.x; xi[j] = v.y;
    }

    // ---- stage 2: DFT-16 over u, twiddle W64^{s*k2a} ----
    dft16(xr, xi);
    {
        float sw, cw;
        sincosf((float)s * -9.817477042468103e-2f, &sw, &cw);   // -2pi s/64
        float ur = 1.0f, ui = 0.0f;
#pragma unroll
        for (int k2 = 1; k2 < 16; ++k2) {
            float nr = ur * cw - ui * sw;
            ui = ur * sw + ui * cw;
            ur = nr;
            float tr = xr[k2] * ur - xi[k2] * ui;
            xi[k2] = xr[k2] * ui + xi[k2] * ur;
            xr[k2] = tr;
        }
    }

    // ---- write E at psi(e), e = g*64 + 4*k2a + s, psi = e ^ ((g&7)<<1) ----
    {
        const int g2 = (g & 7) << 1;
#pragma unroll
        for (int k2 = 0; k2 < 16; ++k2)
            B[g * 64 + ((4 * k2 + s) ^ g2)] = make_float2(xr[k2], xi[k2]);
    }

    // ---- final radix-4 + Hermitian unpack + magnitudes (k = t + 64*jj) ----
    const float4* Bv = (const float4*)buf[w];
    const int gk = t & 15;
    const int g2k = (gk & 7) << 1;
    const int tb = t >> 4;
#pragma unroll
    for (int jj = 0; jj < 8; ++jj) {
        const int k  = t + 64 * jj;                 // 0..511
        const int jk = (tb + 4 * jj) & 15;
        const int e0 = gk * 64 + ((4 * jk) ^ g2k);
        float4 E01 = Bv[e0 >> 1];                   // s=0,1
        float4 E23 = Bv[(e0 ^ 2) >> 1];             // s=2,3
        float S02r = E01.x + E23.x, S02i = E01.y + E23.y;
        float D02r = E01.x - E23.x, D02i = E01.y - E23.y;
        float S13r = E01.z + E23.z, S13i = E01.w + E23.w;
        float D13r = E01.z - E23.z, D13i = E01.w - E23.w;
        float a, b;
        if (jj < 4) { a = S02r + S13r; b = S02i + S13i; }          // bk=0
        else        { a = D02r + D13i; b = D02i - D13r; }          // bk=1: D02 - i*D13
        // partner kN = 1024-k
        const int kN = (1024 - k) & 1023;
        const int gN = kN & 15, jN = (kN >> 4) & 15, bN = kN >> 8;
        const int eN = gN * 64 + ((4 * jN) ^ ((gN & 7) << 1));
        float4 F01 = Bv[eN >> 1];
        float4 F23 = Bv[(eN ^ 2) >> 1];
        float GS02r = F01.x + F23.x, GS02i = F01.y + F23.y;
        float GD02r = F01.x - F23.x, GD02i = F01.y - F23.y;
        float GS13r = F01.z + F23.z, GS13i = F01.w + F23.w;
        float GD13r = F01.z - F23.z, GD13i = F01.w - F23.w;
        const float sE = (bN & 2) ? -1.0f : 1.0f;
        float cEv = GS02r + sE * GS13r, dEv = GS02i + sE * GS13i;  // even bN
        float cOv = GD02r + sE * GD13i, dOv = GD02i - sE * GD13r;  // odd bN
        float c = (bN & 1) ? cOv : cEv;
        float d = (bN & 1) ? dOv : dEv;
        // unpack z = x0 + i x1
        float m0 = 0.5f * sqrtf((a + c) * (a + c) + (b - d) * (b - d));
        float m1 = 0.5f * sqrtf((b + d) * (b + d) + (c - a) * (c - a));
        magb[w][k] = make_float2(m0, m1);
    }
    if (t == 0) {   // k = 512: group (0,0), bk=2, self-paired
        float4 E01 = Bv[0], E23 = Bv[1];
        float a = (E01.x + E23.x) - (E01.z + E23.z);
        float b = (E01.y + E23.y) - (E01.w + E23.w);
        magb[w][512] = make_float2(fabsf(a), fabsf(b));
    }

    // ---- sparse mel projection (both frames at once), 2 filters per lane ----
#pragma unroll
    for (int h = 0; h < 2; ++h) {
        const int m = t + 64 * h;
        const int fs = fstart[m], fe = fend[m];
        const float* fr = fbT + m * FBSTRIDE;
        float a0 = 0.0f, a1 = 0.0f;
        for (int f = fs; f < fe; ++f) {
            float2 mg = magb[w][f];
            float cf = fr[f];
            a0 = fmaf(mg.x, cf, a0);
            a1 = fmaf(mg.y, cf, a1);
        }
        mel[((size_t)(2 * q)     * TFRAMES + tf) * NMELS + m] = a0;
        mel[((size_t)(2 * q + 1) * TFRAMES + tf) * NMELS + m] = a1;
    }
}

// ---------------- kernel 3: PCEN chunked-scan + partial stats (512 blocks) ----------------
#define CHUNKS 8
#define CH0LEN 51            // 401 = 51 + 7*50
#define CHLEN  50
#define AFACT  0.28202481f   // 0.975^50

__launch_bounds__(256)
__global__ void pcen_kernel(const float* __restrict__ mel,
                            float* __restrict__ out,
                            double* __restrict__ partials) {
    const int b   = blockIdx.x >> 2;
    const int mg  = blockIdx.x & 3;
    const int tid = threadIdx.x;
    const int ml  = tid & 31;
    const int c   = tid >> 5;                       // 0..7
    const int m   = mg * 32 + ml;
    const int t0  = (c == 0) ? 0 : (CH0LEN + CHLEN * (c - 1));
    const int len = (c == 0) ? CH0LEN : CHLEN;
    const float* mb = mel + (size_t)b * TFRAMES * NMELS;

    float v[CH0LEN];
#pragma unroll
    for (int i = 0; i < CH0LEN; ++i)
        if (i < len) v[i] = mb[(size_t)(t0 + i) * NMELS + m];

    // pass 1: per-chunk IIR partial with zero carry-in (chunk 0 = true init)
    float M;
    if (c == 0) {
        M = v[0];
#pragma unroll
        for (int i = 1; i < CH0LEN; ++i) M = fmaf(0.975f, M, 0.025f * v[i]);
    } else {
        M = 0.0f;
#pragma unroll
        for (int i = 0; i < CHLEN; ++i) M = fmaf(0.975f, M, 0.025f * v[i]);
    }
    __shared__ float Bc[CHUNKS][32];
    Bc[c][ml] = M;
    __syncthreads();

    float Min = 0.0f;
    if (c > 0) {
        Min = Bc[0][ml];
        for (int k = 1; k < c; ++k) Min = fmaf(AFACT, Min, Bc[k][ml]);
    }

    // pass 2: exact replay from carry; pcen; stats accumulate; unnormalized store
    M = Min;
    float sum = 0.0f, sumsq = 0.0f;
    float* orow = out + (size_t)b * NMELS * TFRAMES + (size_t)m * TFRAMES + t0;
#pragma unroll
    for (int i = 0; i < CH0LEN; ++i) {
        if (i < len) {
            float xt = v[i];
            M = (c == 0 && i == 0) ? xt : fmaf(0.975f, M, 0.025f * xt);
            float smooth = __expf(0.98f * __logf(1e-6f + M));     // (eps+M)^0.98
            float p = sqrtf(xt / smooth + 2.0f) - 1.4142135623730951f;
            orow[i] = p;
            sum += p;
            sumsq = fmaf(p, p, sumsq);
        }
    }

    // block reduction -> unique partial slot (no atomics)
    double s = (double)sum, qq = (double)sumsq;
    for (int off = 32; off > 0; off >>= 1) {
        s  += __shfl_down(s, off);
        qq += __shfl_down(qq, off);
    }
    __shared__ double wsum[4], wsq[4];
    const int wid = tid >> 6, lane = tid & 63;
    if (lane == 0) { wsum[wid] = s; wsq[wid] = qq; }
    __syncthreads();
    if (tid == 0) {
        double S = wsum[0] + wsum[1] + wsum[2] + wsum[3];
        double Q = wsq[0] + wsq[1] + wsq[2] + wsq[3];
        partials[(size_t)(b * 4 + mg) * 2]     = S;
        partials[(size_t)(b * 4 + mg) * 2 + 1] = Q;
    }
}

// ---------------- kernel 4: normalize (full GPU, float4) ----------------
__global__ void norm_kernel(float* __restrict__ out, const double* __restrict__ partials) {
    __shared__ float sh[2];
    const int b = blockIdx.x;
    if (threadIdx.x == 0) {
        double S = 0.0, Q = 0.0;
#pragma unroll
        for (int gg = 0; gg < 4; ++gg) {
            S += partials[(size_t)(b * 4 + gg) * 2];
            Q += partials[(size_t)(b * 4 + gg) * 2 + 1];
        }
        const double n = (double)(NMELS * TFRAMES);
        double mean = S / n;
        double var  = (Q - n * mean * mean) / (n - 1.0);
        double sd   = sqrt(var > 0.0 ? var : 0.0);
        sh[0] = (float)mean;
        sh[1] = (float)(1.0 / (sd + 1e-6));
    }
    __syncthreads();
    const int i4 = blockIdx.y * 256 + threadIdx.x;
    if (i4 >= NMELS * TFRAMES / 4) return;          // 12832
    const float mean = sh[0], inv = sh[1];
    float4* o = (float4*)(out + (size_t)b * NMELS * TFRAMES);
    float4 vv = o[i4];
    vv.x = (vv.x - mean) * inv;
    vv.y = (vv.y - mean) * inv;
    vv.z = (vv.z - mean) * inv;
    vv.w = (vv.w - mean) * inv;
    o[i4] = vv;
}

// ---------------- launch ----------------
extern "C" void kernel_launch(void* const* d_in, const int* in_sizes, int n_in,
                              void* d_out, int out_size, void* d_ws, size_t ws_size,
                              hipStream_t stream) {
    const float* x = (const float*)d_in[0];
    float* out = (float*)d_out;
    float* ws  = (float*)d_ws;

    float*  win    = ws + WS_WIN;
    float*  fbT    = ws + WS_FBT;
    int*    fstart = (int*)(ws + WS_FS);
    int*    fend   = (int*)(ws + WS_FE);
    double* parts  = (double*)(ws + WS_PART);
    float*  mel    = ws + WS_MEL;

    prep_kernel<<<dim3(1), dim3(256), 0, stream>>>(win, fbT, fstart, fend);
    fft_mel_kernel<<<dim3((NB / 2) * TFRAMES / 4), dim3(256), 0, stream>>>(
        x, win, fbT, fstart, fend, mel);
    pcen_kernel<<<dim3(NB * 4), dim3(256), 0, stream>>>(mel, out, parts);
    norm_kernel<<<dim3(NB, 51), dim3(256), 0, stream>>>(out, parts);
}